// Round 1
// 99.934 us; speedup vs baseline: 1.1352x; 1.1352x over previous
//
#include <hip/hip_runtime.h>

// MMD loss, class-compacted (r14). 3 nodes: memset(12KB), k_fused, k_pairs.
// r14 changes vs r13 (113.4us):
//  (1) k_colsum DELETED. It only fed ns=||sum x||^2 per class. k_pairs now
//      grid (C,8): each block computes ns cooperatively from the bf16 panels
//      with COALESCED ushort8 loads (write-order), bw computed ONCE per
//      block into LDS (was per-tile colsum load + 64-lane butterfly, plus a
//      serial 31-class prefix scan on thread 0 of every one of 208 blocks).
//  (2) k_fused lane-0 tail: rank atomicAdd, ssum float atomicAdd, and flag
//      check previously ALL hit the same 128B line per class (~264 serialized
//      RMWs/line). Now split into 3 separate padded line regions ->
//      3x31 independent TCC streams.
//  (3) k_fused grid 768->1024: 4096 waves for 4096 rows, no second-row tail.
// NOTE: top-5 rocprof dispatches are the harness's fixed 256MiB workspace
// poison fills (41.7us @80% HBM peak) - NOT controllable from kernel source;
// they are a floor inside dur_us.
// DO NOT reintroduce: r9 persistent grid-barrier (434us); r5 per-element
// colsum atomics (34MB writes); r2 per-block fences at 6144 grid; r12
// unpadded per-row atomics (54us k_fused); r13 shared rank/ssum/flag line.
// Math verified absmax 0.0 r1-r13: class bucketing, upper-tri tiles w/ 2x
// off-diag, m@D@m = 2n*sum(sq)-2*||sum x||^2, MFMA C/D map col=lane&31,
// row=(reg&3)+8*(reg>>2)+4*(lane>>5). Panel layout: class c base c*RCAP
// rows; 32-row panels; chunk m (cols m*8..m*8+7) of row i at
// panel*D + (m>>1)*512 + ((m&1)*32 + (i&31))*8.

#define CMAX 32
#define RCAP 6144      // fixed rows per class region (worst case N=6144)
#define PCW 32         // ints per padded counter line (128B)
#define PAIR_Y 8       // blocks per class in k_pairs

typedef __attribute__((ext_vector_type(8)))  short  short8;
typedef __attribute__((ext_vector_type(8)))  unsigned short ushort8;
typedef __attribute__((ext_vector_type(16))) float  float16;

__device__ inline unsigned short f2bf(float x) {  // fp32 -> bf16 RNE
  unsigned u = __float_as_uint(x);
  return (unsigned short)((u + 0x7FFFu + ((u >> 16) & 1u)) >> 16);
}

// ---- K1: wave-per-row single pass: label + rank + sq + bf16 panel write ----
// Counter layout (all padded to one 128B line per class, SEPARATE regions):
//   pc[c*PCW]              rank counter (row allocation)
//   pc[(CMAX+c)*PCW]       float ssum (sum of row sq-norms)
//   pc[(2*CMAX+c)*PCW]+0/1 src/tgt presence flags
__global__ __launch_bounds__(256) void k_fused(
    const float* __restrict__ src, const float* __restrict__ tgt,
    const int* __restrict__ slab, const float* __restrict__ tlabel,
    const int* __restrict__ nsd_p,
    int* pc,
    unsigned short* __restrict__ fragbuf,
    float* __restrict__ sqc, float* __restrict__ sgnc,
    int S_total, int T, int D, int C) {
  int lane = threadIdx.x & 63;
  int gwid = (blockIdx.x * 256 + threadIdx.x) >> 6;
  int nwv = (gridDim.x * 256) >> 6;
  int nsd = nsd_p[0];
  int S_use = S_total - nsd;
  int N = S_use + T;

  for (int r = gwid; r < N; r += nwv) {
    int c;
    const float* row;
    bool isSrc = (r < S_use);
    if (isSrc) {
      c = slab[nsd + r];
      row = src + (size_t)(nsd + r) * D;
    } else {
      int t = r - S_use;
      row = tgt + (size_t)t * D;
      float v = (lane < C) ? tlabel[(size_t)t * C + lane] : -3.4e38f;
      int idx = lane;
      for (int o = 32; o > 0; o >>= 1) {
        float ov = __shfl_down(v, o, 64);
        int oi = __shfl_down(idx, o, 64);
        if (ov > v || (ov == v && oi < idx)) { v = ov; idx = oi; }
      }
      c = __shfl(idx, 0, 64);
    }
    const float4* s4 = (const float4*)row;
    int nm = D >> 3;
    float4 v0, v1;
    if (lane < nm) { v0 = s4[lane * 2]; v1 = s4[lane * 2 + 1]; }  // in flight

    int rk;
    if (lane == 0) rk = atomicAdd(&pc[c * PCW], 1);   // own 128B line/class
    rk = __shfl(rk, 0, 64);
    int p = c * RCAP + rk;
    unsigned short* pb = fragbuf + (size_t)(c * RCAP + (rk & ~31)) * D;
    int row32 = rk & 31;

    float s = 0.f;
    if (lane < nm) {
      s += v0.x * v0.x + v0.y * v0.y + v0.z * v0.z + v0.w * v0.w +
           v1.x * v1.x + v1.y * v1.y + v1.z * v1.z + v1.w * v1.w;
      ushort8 h;
      h[0] = f2bf(v0.x); h[1] = f2bf(v0.y); h[2] = f2bf(v0.z); h[3] = f2bf(v0.w);
      h[4] = f2bf(v1.x); h[5] = f2bf(v1.y); h[6] = f2bf(v1.z); h[7] = f2bf(v1.w);
      int st = lane >> 1, hf = lane & 1;
      *(ushort8*)(pb + st * 512 + (hf * 32 + row32) * 8) = h;
    }
    for (int m = lane + 64; m < nm; m += 64) {   // D>512 fallback (not hit)
      float4 w0 = s4[m * 2], w1 = s4[m * 2 + 1];
      s += w0.x * w0.x + w0.y * w0.y + w0.z * w0.z + w0.w * w0.w +
           w1.x * w1.x + w1.y * w1.y + w1.z * w1.z + w1.w * w1.w;
      ushort8 h;
      h[0] = f2bf(w0.x); h[1] = f2bf(w0.y); h[2] = f2bf(w0.z); h[3] = f2bf(w0.w);
      h[4] = f2bf(w1.x); h[5] = f2bf(w1.y); h[6] = f2bf(w1.z); h[7] = f2bf(w1.w);
      int st = m >> 1, hf = m & 1;
      *(ushort8*)(pb + st * 512 + (hf * 32 + row32) * 8) = h;
    }
    for (int o = 32; o > 0; o >>= 1) s += __shfl_down(s, o, 64);
    if (lane == 0) {
      sqc[p] = s;
      sgnc[p] = isSrc ? 1.f : -1.f;
      atomicAdd((float*)&pc[(CMAX + c) * PCW], s);            // own line
      int* flag = &pc[(2 * CMAX + c) * PCW + (isSrc ? 0 : 1)]; // own line
      if (*(volatile int*)flag == 0) atomicExch(flag, 1);      // set-once
    }
  }
}

// ---- K2: per-class ns+bw (once per block) + MFMA pair tiles + final fold ----
// grid (C, PAIR_Y): block (c,y) computes ns for class c cooperatively
// (coalesced ushort8 reads in panel write-order), bw once into LDS, then its
// 4 waves process tiles y*4+w, stride PAIR_Y*4.
__global__ __launch_bounds__(256) void k_pairs(
    const unsigned short* __restrict__ fragbuf, const float* __restrict__ sqc,
    const float* __restrict__ sgnc, const int* __restrict__ pc,
    float* losssum, int* done, float* __restrict__ out, int D, int C) {
  __shared__ float scs[4][64][8];
  __shared__ float s_inv0;
  __shared__ int lastFlag;
  int c = blockIdx.x;
  int tid = threadIdx.x;
  int n = pc[c * PCW];
  int off = c * RCAP;
  const unsigned short* base = fragbuf + (size_t)off * D;
  int nm = D >> 3;

  // ns = ||sum_i x_i||^2 from bf16 panels. Thread owns chunk cl (cols
  // cl*8..cl*8+7) for rows i == rg (mod 4); coalesced 16B loads.
  int rg = tid >> 6, cl = tid & 63;
  float nspart = 0.f;
  for (int m0 = 0; m0 < nm; m0 += 64) {     // one pass at D=512
    int m = m0 + cl;
    float cs[8] = {0.f, 0.f, 0.f, 0.f, 0.f, 0.f, 0.f, 0.f};
    if (m < nm) {
      int st = m >> 1, hf = m & 1;
      for (int i = rg; i < n; i += 4) {
        ushort8 v = *(const ushort8*)(base + (size_t)(i & ~31) * D +
                                      st * 512 + (hf * 32 + (i & 31)) * 8);
        #pragma unroll
        for (int j = 0; j < 8; j++)
          cs[j] += __uint_as_float((unsigned)v[j] << 16);
      }
    }
    #pragma unroll
    for (int j = 0; j < 8; j++) scs[rg][cl][j] = cs[j];
    __syncthreads();
    if (tid < 64) {
      #pragma unroll
      for (int j = 0; j < 8; j++) {
        float t = scs[0][tid][j] + scs[1][tid][j] +
                  scs[2][tid][j] + scs[3][tid][j];
        nspart += t * t;
      }
    }
    __syncthreads();
  }
  if (tid < 64) {
    for (int o = 32; o > 0; o >>= 1) nspart += __shfl_down(nspart, o, 64);
    if (tid == 0) {
      float ss = ((const float*)pc)[(CMAX + c) * PCW];
      float nf = (float)n;
      float S1 = 2.f * nf * ss - 2.f * nspart;   // == m @ Dmat @ m
      float bw = S1 / fmaxf(nf * nf - nf, 1.f);
      bw = (bw > 0.f) ? bw : 1.f;
      s_inv0 = 4.f / bw;                         // 1 / (bw * 0.25)
    }
  }
  __syncthreads();
  float inv0 = s_inv0;

  int tpr = (n + 31) >> 5;
  int tiles = tpr * (tpr + 1) / 2;
  int lane = tid & 63, l31 = lane & 31, half = lane >> 5;
  int wvc = blockIdx.y * 4 + (tid >> 6);
  int nwvc = gridDim.y * 4;
  float wsum = 0.f;

  for (int t = wvc; t < tiles; t += nwvc) {
    int lt = t, jt = 0;
    while (lt >= tpr - jt) { lt -= tpr - jt; jt++; }
    int kt = jt + lt;
    int jbase = jt << 5, kbase = kt << 5;
    float wgt = (jt == kt) ? 1.f : 2.f;

    const unsigned short* fa  = fragbuf + (size_t)(off + jbase) * D + lane * 8;
    const unsigned short* fbp = fragbuf + (size_t)(off + kbase) * D + lane * 8;
    float16 acc = {};
    if (D == 512) {
      #pragma unroll
      for (int s = 0; s < 32; s++) {
        short8 a = *(const short8*)(fa + s * 512);
        short8 b = *(const short8*)(fbp + s * 512);
        acc = __builtin_amdgcn_mfma_f32_32x32x16_bf16(a, b, acc, 0, 0, 0);
      }
    } else {
      for (int s = 0; s < (D >> 4); s++) {
        short8 a = *(const short8*)(fa + s * 512);
        short8 b = *(const short8*)(fbp + s * 512);
        acc = __builtin_amdgcn_mfma_f32_32x32x16_bf16(a, b, acc, 0, 0, 0);
      }
    }

    float sqk = sqc[off + kbase + l31];
    float sgk = sgnc[off + kbase + l31];
    bool kval = (kbase + l31) < n;
    float sqjv = sqc[off + jbase + l31];
    float sgjv = sgnc[off + jbase + l31];
    float contrib = 0.f;
    #pragma unroll
    for (int r = 0; r < 16; r++) {
      int m = (r & 3) + 8 * (r >> 2) + 4 * half;
      float sqj = __shfl(sqjv, m, 64);
      float sgj = __shfl(sgjv, m, 64);
      if (kval && (jbase + m) < n) {
        float d = fmaxf(sqj + sqk - 2.f * acc[r], 0.f);
        float s = inv0, kv = 0.f;
        #pragma unroll
        for (int q = 0; q < 5; q++) { kv += __expf(-d * s); s *= 0.5f; }
        contrib += sgj * sgk * kv;
      }
    }
    wsum += wgt * contrib;
  }
  for (int o = 32; o > 0; o >>= 1) wsum += __shfl_down(wsum, o, 64);
  if (lane == 0 && wsum != 0.f) atomicAdd(&losssum[c], wsum);

  // last-block fold -> final scalar (one fence+atomic per BLOCK)
  __syncthreads();
  if (tid == 0) {
    __threadfence();
    int d = atomicAdd(done, 1);
    lastFlag = (d == (int)(gridDim.x * gridDim.y) - 1);
  }
  __syncthreads();
  if (lastFlag && tid < 64) {
    int cc = tid;
    float loss = 0.f, cv = 0.f;
    if (cc < C && pc[(2 * CMAX + cc) * PCW] > 0 &&
        pc[(2 * CMAX + cc) * PCW + 1] > 0) {
      float nf = (float)pc[cc * PCW];
      loss = atomicAdd(&losssum[cc], 0.f) / fmaxf(nf * nf, 1.f);  // coherent
      cv = 1.f;
    }
    for (int o = 32; o > 0; o >>= 1) {
      loss += __shfl_down(loss, o, 64);
      cv   += __shfl_down(cv, o, 64);
    }
    if (tid == 0) out[0] = loss / fmaxf(cv, 1.f);
  }
}

extern "C" void kernel_launch(void* const* d_in, const int* in_sizes, int n_in,
                              void* d_out, int out_size, void* d_ws, size_t ws_size,
                              hipStream_t stream) {
  const float* source = (const float*)d_in[0];
  const float* target = (const float*)d_in[1];
  const int* slab     = (const int*)d_in[2];
  const float* tlabel = (const float*)d_in[3];
  const int* nsd_p    = (const int*)d_in[4];
  float* out = (float*)d_out;

  int S_total = in_sizes[2];
  int D = in_sizes[0] / S_total;   // 512
  int T = in_sizes[1] / D;         // 2048
  int C = in_sizes[3] / T;         // 31

  // workspace layout (4-byte words); zeroed-by-memset region first (12.4KB)
  int* ws = (int*)d_ws;
  int* pc       = ws;                               // 3*CMAX*PCW padded lines
  float* losssum = (float*)(ws + 3 * CMAX * PCW);   // C
  int* done     = (int*)(losssum + C);              // 8
  int zwords    = 3 * CMAX * PCW + C + 8;

  float* sqc    = (float*)(ws + zwords);            // C*RCAP
  float* sgnc   = sqc + (size_t)C * RCAP;           // C*RCAP
  size_t words_used = (size_t)zwords + 2 * (size_t)C * RCAP;
  size_t fw = (words_used + 63) & ~(size_t)63;      // 256B-align fragbuf
  unsigned short* fragbuf = (unsigned short*)(ws + fw);  // C*RCAP*D bf16

  hipMemsetAsync(d_ws, 0, (size_t)zwords * sizeof(int), stream);

  k_fused<<<1024, 256, 0, stream>>>(source, target, slab, tlabel, nsd_p,
                                    pc, fragbuf, sqc, sgnc,
                                    S_total, T, D, C);
  k_pairs<<<dim3(C, PAIR_Y), 256, 0, stream>>>(fragbuf, sqc, sgnc, pc,
                                               losssum, done, out, D, C);
}